// Round 1
// baseline (794.332 us; speedup 1.0000x reference)
//
#include <hip/hip_runtime.h>

#define BATCH   4
#define NPTS    4096
#define MPTS    4096
#define NSTEPS  16
#define ICP_TOL 1e-6f
#define MCHUNK  512

// ---------- small double-precision helpers for the 3x3 Kabsch ----------

__device__ inline void normalize3d(double v[3]) {
    double n = sqrt(v[0]*v[0] + v[1]*v[1] + v[2]*v[2]);
    double inv = (n > 1e-300) ? 1.0 / n : 0.0;
    v[0] *= inv; v[1] *= inv; v[2] *= inv;
}

__device__ inline void cross3d(const double a[3], const double b[3], double c[3]) {
    c[0] = a[1]*b[2] - a[2]*b[1];
    c[1] = a[2]*b[0] - a[0]*b[2];
    c[2] = a[0]*b[1] - a[1]*b[0];
}

// eigenvector of K for the eigenvalue NOT in {la, lb}: any nonzero column of
// (K - la I)(K - lb I) is proportional to it (spectral projector).
__device__ inline void eigvec_from_product(const double K[3][3], double la, double lb, double v[3]) {
    double A[3][3], Bm[3][3], C[3][3];
    for (int i = 0; i < 3; i++)
        for (int j = 0; j < 3; j++) {
            A[i][j]  = K[i][j] - ((i == j) ? la : 0.0);
            Bm[i][j] = K[i][j] - ((i == j) ? lb : 0.0);
        }
    for (int i = 0; i < 3; i++)
        for (int j = 0; j < 3; j++) {
            double s = 0.0;
            for (int k = 0; k < 3; k++) s += A[i][k] * Bm[k][j];
            C[i][j] = s;
        }
    int best = 0; double bn = -1.0;
    for (int c = 0; c < 3; c++) {
        double n2 = C[0][c]*C[0][c] + C[1][c]*C[1][c] + C[2][c]*C[2][c];
        if (n2 > bn) { bn = n2; best = c; }
    }
    if (bn > 1e-280) {
        double inv = 1.0 / sqrt(bn);
        v[0] = C[0][best]*inv; v[1] = C[1][best]*inv; v[2] = C[2][best]*inv;
    } else {
        v[0] = 1.0; v[1] = 0.0; v[2] = 0.0;
    }
}

// S[0:3]=sum p, S[3:6]=sum q, S[6:15]=sum p_i q_j (row-major), from N points.
// Produces optimal proper rotation R (q ~ R p + t) and translation t.
// Equivalent to reference Kabsch: H=U S V^T, R=V diag(1,1,det(VU^T)) U^T.
__device__ inline void kabsch_from_sums(const double S[16], double R[3][3], double t[3]) {
    const double inv_n = 1.0 / (double)NPTS;
    double cs[3] = { S[0]*inv_n, S[1]*inv_n, S[2]*inv_n };
    double ct[3] = { S[3]*inv_n, S[4]*inv_n, S[5]*inv_n };
    double H[3][3];
    for (int i = 0; i < 3; i++)
        for (int j = 0; j < 3; j++)
            H[i][j] = S[6 + 3*i + j] - S[i]*S[3 + j]*inv_n;

    // K = H^T H (symmetric PSD)
    double K[3][3];
    for (int i = 0; i < 3; i++)
        for (int j = 0; j < 3; j++) {
            double s = 0.0;
            for (int k = 0; k < 3; k++) s += H[k][i]*H[k][j];
            K[i][j] = s;
        }

    // closed-form eigenvalues (trigonometric method), l1 >= l2 >= l3
    double q = (K[0][0] + K[1][1] + K[2][2]) / 3.0;
    double p1 = K[0][1]*K[0][1] + K[0][2]*K[0][2] + K[1][2]*K[1][2];
    double a00 = K[0][0]-q, a11 = K[1][1]-q, a22 = K[2][2]-q;
    double p2 = a00*a00 + a11*a11 + a22*a22 + 2.0*p1;
    double p = sqrt(p2 / 6.0);
    double l1, l2, l3;
    if (p < 1e-150) {
        l1 = l2 = l3 = q;
    } else {
        double ip = 1.0 / p;
        double b00 = a00*ip, b01 = K[0][1]*ip, b02 = K[0][2]*ip;
        double b11 = a11*ip, b12 = K[1][2]*ip, b22 = a22*ip;
        double detB = b00*(b11*b22 - b12*b12)
                    - b01*(b01*b22 - b12*b02)
                    + b02*(b01*b12 - b11*b02);
        double r = 0.5 * detB;
        r = r < -1.0 ? -1.0 : (r > 1.0 ? 1.0 : r);
        double phi = acos(r) / 3.0;
        l1 = q + 2.0*p*cos(phi);
        l3 = q + 2.0*p*cos(phi + 2.0943951023931953); // +2pi/3
        l2 = 3.0*q - l1 - l3;
    }

    double v1[3], v2[3], v3[3];
    eigvec_from_product(K, l2, l3, v1);
    eigvec_from_product(K, l1, l3, v2);
    // re-orthogonalize v2 against v1 for numerical safety
    double d12 = v1[0]*v2[0] + v1[1]*v2[1] + v1[2]*v2[2];
    for (int i = 0; i < 3; i++) v2[i] -= d12*v1[i];
    normalize3d(v2);
    cross3d(v1, v2, v3);  // det V = +1

    double u1[3], u2[3], u3[3];
    for (int i = 0; i < 3; i++) u1[i] = H[i][0]*v1[0] + H[i][1]*v1[1] + H[i][2]*v1[2];
    normalize3d(u1);
    for (int i = 0; i < 3; i++) u2[i] = H[i][0]*v2[0] + H[i][1]*v2[1] + H[i][2]*v2[2];
    double du = u1[0]*u2[0] + u1[1]*u2[1] + u1[2]*u2[2];
    for (int i = 0; i < 3; i++) u2[i] -= du*u1[i];
    normalize3d(u2);
    cross3d(u1, u2, u3);  // det U = +1; signed-SVD form => R = V U^T is optimal proper rotation

    for (int i = 0; i < 3; i++)
        for (int j = 0; j < 3; j++)
            R[i][j] = v1[i]*u1[j] + v2[i]*u2[j] + v3[i]*u3[j];
    for (int i = 0; i < 3; i++)
        t[i] = ct[i] - (R[i][0]*cs[0] + R[i][1]*cs[1] + R[i][2]*cs[2]);
}

// ------------------------------- kernels -------------------------------

__global__ void k_init(const float* __restrict__ src, float* __restrict__ temporal,
                       unsigned long long* __restrict__ nn,
                       float* __restrict__ errlast, int* __restrict__ done) {
    int i = blockIdx.x * blockDim.x + threadIdx.x;   // 0 .. BATCH*NPTS-1
    if (i < BATCH*NPTS) {
        temporal[3*i+0] = src[3*i+0];
        temporal[3*i+1] = src[3*i+1];
        temporal[3*i+2] = src[3*i+2];
        nn[i] = ~0ull;
    }
    if (i < BATCH) errlast[i] = 0.0f;
    if (i == 0) *done = 0;
}

// grid: (MPTS/MCHUNK, NPTS/256, BATCH), block 256
__global__ void k_nn(const float* __restrict__ temporal, const float* __restrict__ target,
                     unsigned long long* __restrict__ nn, const int* __restrict__ done) {
    if (*done) return;
    __shared__ float4 st[MCHUNK];
    const int b  = blockIdx.z;
    const int m0 = blockIdx.x * MCHUNK;
    const int n  = blockIdx.y * 256 + threadIdx.x;

    const float* tg = target + ((size_t)b*MPTS + m0)*3;
    for (int i = threadIdx.x; i < MCHUNK*3; i += 256) {
        int pt = i / 3, c = i % 3;
        ((float*)&st[pt])[c] = tg[i];
    }
    __syncthreads();

    const float* tp = temporal + ((size_t)b*NPTS + n)*3;
    float px = tp[0], py = tp[1], pz = tp[2];
    float bestd = 1e30f; int bestm = 0;
    #pragma unroll 8
    for (int m = 0; m < MCHUNK; ++m) {
        float4 t4 = st[m];
        float dx = px - t4.x, dy = py - t4.y, dz = pz - t4.z;
        float d2 = dx*dx + dy*dy + dz*dz;
        if (d2 < bestd) { bestd = d2; bestm = m; }   // keeps FIRST min (argmin tie rule)
    }
    unsigned long long key = ((unsigned long long)__float_as_uint(bestd) << 32)
                           | (unsigned)(m0 + bestm);
    atomicMin(&nn[(size_t)b*NPTS + n], key);
}

// single block, 1024 threads: per-batch sums -> convergence check -> Kabsch
__global__ void k_reduce(const float* __restrict__ temporal, const float* __restrict__ target,
                         const unsigned long long* __restrict__ nn,
                         float* __restrict__ Rt, float* __restrict__ errlast,
                         int* __restrict__ done) {
    if (*done) return;
    const int tid = threadIdx.x;
    const int b = tid >> 8;          // 256 threads per batch
    const int lb = tid & 255;

    double acc[16];
    #pragma unroll
    for (int i = 0; i < 16; i++) acc[i] = 0.0;

    for (int k = 0; k < NPTS/256; ++k) {
        int n = lb + k*256;
        unsigned long long key = nn[(size_t)b*NPTS + n];
        int idx = (int)(key & 0xffffffffull);
        float d2 = __uint_as_float((unsigned)(key >> 32));
        const float* tp = temporal + ((size_t)b*NPTS + n)*3;
        const float* tq = target   + ((size_t)b*MPTS + idx)*3;
        double px = tp[0], py = tp[1], pz = tp[2];
        double qx = tq[0], qy = tq[1], qz = tq[2];
        acc[0] += px;  acc[1] += py;  acc[2] += pz;
        acc[3] += qx;  acc[4] += qy;  acc[5] += qz;
        acc[6] += px*qx;  acc[7]  += px*qy;  acc[8]  += px*qz;
        acc[9] += py*qx;  acc[10] += py*qy;  acc[11] += py*qz;
        acc[12]+= pz*qx;  acc[13] += pz*qy;  acc[14] += pz*qz;
        acc[15] += sqrt((double)d2);
    }

    // wave(64)-level reduction
    #pragma unroll
    for (int off = 32; off > 0; off >>= 1)
        #pragma unroll
        for (int i = 0; i < 16; i++) acc[i] += __shfl_down(acc[i], off);

    __shared__ double part[16][16];  // [wave][val]
    __shared__ float  lds_err[BATCH];
    __shared__ int    lds_done;
    const int wave = tid >> 6;
    if ((tid & 63) == 0) {
        #pragma unroll
        for (int i = 0; i < 16; i++) part[wave][i] = acc[i];
    }
    __syncthreads();

    double S[16];
    float errnew = 0.0f;
    if (tid < BATCH) {
        #pragma unroll
        for (int i = 0; i < 16; i++)
            S[i] = part[tid*4][i] + part[tid*4+1][i] + part[tid*4+2][i] + part[tid*4+3][i];
        errnew = (float)(S[15] / (double)NPTS);
        lds_err[tid] = errnew;
    }
    __syncthreads();
    if (tid == 0) {
        bool conv = true;
        for (int bb = 0; bb < BATCH; bb++)
            conv = conv && (fabsf(lds_err[bb] - errlast[bb]) < ICP_TOL);
        int d = conv ? 1 : 0;
        *done = d;
        lds_done = d;
    }
    __syncthreads();
    if (tid < BATCH && !lds_done) {
        errlast[tid] = errnew;
        double R[3][3], t[3];
        kabsch_from_sums(S, R, t);
        float* o = Rt + tid*12;
        o[0] = (float)R[0][0]; o[1] = (float)R[0][1]; o[2] = (float)R[0][2];
        o[3] = (float)R[1][0]; o[4] = (float)R[1][1]; o[5] = (float)R[1][2];
        o[6] = (float)R[2][0]; o[7] = (float)R[2][1]; o[8] = (float)R[2][2];
        o[9] = (float)t[0];    o[10] = (float)t[1];   o[11] = (float)t[2];
    }
}

__global__ void k_transform(float* __restrict__ temporal, const float* __restrict__ Rt,
                            unsigned long long* __restrict__ nn, const int* __restrict__ done) {
    int i = blockIdx.x * blockDim.x + threadIdx.x;
    if (i >= BATCH*NPTS) return;
    nn[i] = ~0ull;                    // reset keys for next step (always)
    if (*done) return;                // frozen state
    int b = i >> 12;                  // / NPTS
    const float* rt = Rt + b*12;
    float* tp = temporal + (size_t)i*3;
    float x = tp[0], y = tp[1], z = tp[2];
    tp[0] = rt[0]*x + rt[1]*y + rt[2]*z + rt[9];
    tp[1] = rt[3]*x + rt[4]*y + rt[5]*z + rt[10];
    tp[2] = rt[6]*x + rt[7]*y + rt[8]*z + rt[11];
}

// final Kabsch: source -> temporal (identity correspondence), writes [B,3,4]
__global__ void k_final(const float* __restrict__ source, const float* __restrict__ temporal,
                        float* __restrict__ out) {
    const int tid = threadIdx.x;
    const int b = tid >> 8;
    const int lb = tid & 255;

    double acc[16];
    #pragma unroll
    for (int i = 0; i < 16; i++) acc[i] = 0.0;

    for (int k = 0; k < NPTS/256; ++k) {
        int n = lb + k*256;
        const float* tp = source   + ((size_t)b*NPTS + n)*3;
        const float* tq = temporal + ((size_t)b*NPTS + n)*3;
        double px = tp[0], py = tp[1], pz = tp[2];
        double qx = tq[0], qy = tq[1], qz = tq[2];
        acc[0] += px;  acc[1] += py;  acc[2] += pz;
        acc[3] += qx;  acc[4] += qy;  acc[5] += qz;
        acc[6] += px*qx;  acc[7]  += px*qy;  acc[8]  += px*qz;
        acc[9] += py*qx;  acc[10] += py*qy;  acc[11] += py*qz;
        acc[12]+= pz*qx;  acc[13] += pz*qy;  acc[14] += pz*qz;
    }

    #pragma unroll
    for (int off = 32; off > 0; off >>= 1)
        #pragma unroll
        for (int i = 0; i < 15; i++) acc[i] += __shfl_down(acc[i], off);

    __shared__ double part[16][16];
    const int wave = tid >> 6;
    if ((tid & 63) == 0) {
        #pragma unroll
        for (int i = 0; i < 15; i++) part[wave][i] = acc[i];
    }
    __syncthreads();

    if (tid < BATCH) {
        double S[16];
        #pragma unroll
        for (int i = 0; i < 15; i++)
            S[i] = part[tid*4][i] + part[tid*4+1][i] + part[tid*4+2][i] + part[tid*4+3][i];
        S[15] = 0.0;
        double R[3][3], t[3];
        kabsch_from_sums(S, R, t);
        float* o = out + tid*12;
        for (int i = 0; i < 3; i++) {
            o[i*4+0] = (float)R[i][0];
            o[i*4+1] = (float)R[i][1];
            o[i*4+2] = (float)R[i][2];
            o[i*4+3] = (float)t[i];
        }
    }
}

// ----------------------------- launcher -----------------------------

extern "C" void kernel_launch(void* const* d_in, const int* in_sizes, int n_in,
                              void* d_out, int out_size, void* d_ws, size_t ws_size,
                              hipStream_t stream) {
    const float* src = (const float*)d_in[0];
    const float* tgt = (const float*)d_in[1];
    float* out = (float*)d_out;

    char* ws = (char*)d_ws;
    float* temporal            = (float*)ws;                        // B*N*3 f32 = 196608 B
    unsigned long long* nn     = (unsigned long long*)(ws + 196608); // B*N u64 = 131072 B
    float* Rt                  = (float*)(ws + 327680);              // B*12 f32 = 192 B
    float* errlast             = (float*)(ws + 327872);              // B f32
    int*   done                = (int*)(ws + 327888);                // 1 int

    k_init<<<dim3((BATCH*NPTS + 255)/256), 256, 0, stream>>>(src, temporal, nn, errlast, done);

    for (int s = 0; s < NSTEPS; ++s) {
        k_nn<<<dim3(MPTS/MCHUNK, NPTS/256, BATCH), 256, 0, stream>>>(temporal, tgt, nn, done);
        k_reduce<<<1, 1024, 0, stream>>>(temporal, tgt, nn, Rt, errlast, done);
        k_transform<<<dim3((BATCH*NPTS + 255)/256), 256, 0, stream>>>(temporal, Rt, nn, done);
    }

    k_final<<<1, 1024, 0, stream>>>(src, temporal, out);
}

// Round 3
// 557.391 us; speedup vs baseline: 1.4251x; 1.4251x over previous
//
#include <hip/hip_runtime.h>

#define BATCH   4
#define NPTS    4096
#define MPTS    4096
#define NSTEPS  16
#define ICP_TOL 1e-6f

#define TPB         256
#define NBLOCKS     512      // 128 blocks per batch x 4 batches
#define BLK_PER_B   128
#define PTS_PER_BLK 32       // 4 waves/block, 8 points per wave
#define CHUNK       2048     // targets staged in LDS per chunk (32 KB float4)
#define NCHUNK      (MPTS/CHUNK)

// ---------- double-precision 3x3 Kabsch (verified in round 1) ----------

__device__ inline void normalize3d(double v[3]) {
    double n = sqrt(v[0]*v[0] + v[1]*v[1] + v[2]*v[2]);
    double inv = (n > 1e-300) ? 1.0 / n : 0.0;
    v[0] *= inv; v[1] *= inv; v[2] *= inv;
}

__device__ inline void cross3d(const double a[3], const double b[3], double c[3]) {
    c[0] = a[1]*b[2] - a[2]*b[1];
    c[1] = a[2]*b[0] - a[0]*b[2];
    c[2] = a[0]*b[1] - a[1]*b[0];
}

__device__ inline void eigvec_from_product(const double K[3][3], double la, double lb, double v[3]) {
    double A[3][3], Bm[3][3], C[3][3];
    for (int i = 0; i < 3; i++)
        for (int j = 0; j < 3; j++) {
            A[i][j]  = K[i][j] - ((i == j) ? la : 0.0);
            Bm[i][j] = K[i][j] - ((i == j) ? lb : 0.0);
        }
    for (int i = 0; i < 3; i++)
        for (int j = 0; j < 3; j++) {
            double s = 0.0;
            for (int k = 0; k < 3; k++) s += A[i][k] * Bm[k][j];
            C[i][j] = s;
        }
    int best = 0; double bn = -1.0;
    for (int c = 0; c < 3; c++) {
        double n2 = C[0][c]*C[0][c] + C[1][c]*C[1][c] + C[2][c]*C[2][c];
        if (n2 > bn) { bn = n2; best = c; }
    }
    if (bn > 1e-280) {
        double inv = 1.0 / sqrt(bn);
        v[0] = C[0][best]*inv; v[1] = C[1][best]*inv; v[2] = C[2][best]*inv;
    } else {
        v[0] = 1.0; v[1] = 0.0; v[2] = 0.0;
    }
}

__device__ inline void kabsch_from_sums(const double S[16], double R[3][3], double t[3]) {
    const double inv_n = 1.0 / (double)NPTS;
    double cs[3] = { S[0]*inv_n, S[1]*inv_n, S[2]*inv_n };
    double ct[3] = { S[3]*inv_n, S[4]*inv_n, S[5]*inv_n };
    double H[3][3];
    for (int i = 0; i < 3; i++)
        for (int j = 0; j < 3; j++)
            H[i][j] = S[6 + 3*i + j] - S[i]*S[3 + j]*inv_n;

    double K[3][3];
    for (int i = 0; i < 3; i++)
        for (int j = 0; j < 3; j++) {
            double s = 0.0;
            for (int k = 0; k < 3; k++) s += H[k][i]*H[k][j];
            K[i][j] = s;
        }

    double q = (K[0][0] + K[1][1] + K[2][2]) / 3.0;
    double p1 = K[0][1]*K[0][1] + K[0][2]*K[0][2] + K[1][2]*K[1][2];
    double a00 = K[0][0]-q, a11 = K[1][1]-q, a22 = K[2][2]-q;
    double p2 = a00*a00 + a11*a11 + a22*a22 + 2.0*p1;
    double p = sqrt(p2 / 6.0);
    double l1, l2, l3;
    if (p < 1e-150) {
        l1 = l2 = l3 = q;
    } else {
        double ip = 1.0 / p;
        double b00 = a00*ip, b01 = K[0][1]*ip, b02 = K[0][2]*ip;
        double b11 = a11*ip, b12 = K[1][2]*ip, b22 = a22*ip;
        double detB = b00*(b11*b22 - b12*b12)
                    - b01*(b01*b22 - b12*b02)
                    + b02*(b01*b12 - b11*b02);
        double r = 0.5 * detB;
        r = r < -1.0 ? -1.0 : (r > 1.0 ? 1.0 : r);
        double phi = acos(r) / 3.0;
        l1 = q + 2.0*p*cos(phi);
        l3 = q + 2.0*p*cos(phi + 2.0943951023931953);
        l2 = 3.0*q - l1 - l3;
    }

    double v1[3], v2[3], v3[3];
    eigvec_from_product(K, l2, l3, v1);
    eigvec_from_product(K, l1, l3, v2);
    double d12 = v1[0]*v2[0] + v1[1]*v2[1] + v1[2]*v2[2];
    for (int i = 0; i < 3; i++) v2[i] -= d12*v1[i];
    normalize3d(v2);
    cross3d(v1, v2, v3);

    double u1[3], u2[3], u3[3];
    for (int i = 0; i < 3; i++) u1[i] = H[i][0]*v1[0] + H[i][1]*v1[1] + H[i][2]*v1[2];
    normalize3d(u1);
    for (int i = 0; i < 3; i++) u2[i] = H[i][0]*v2[0] + H[i][1]*v2[1] + H[i][2]*v2[2];
    double du = u1[0]*u2[0] + u1[1]*u2[1] + u1[2]*u2[2];
    for (int i = 0; i < 3; i++) u2[i] -= du*u1[i];
    normalize3d(u2);
    cross3d(u1, u2, u3);

    for (int i = 0; i < 3; i++)
        for (int j = 0; j < 3; j++)
            R[i][j] = v1[i]*u1[j] + v2[i]*u2[j] + v3[i]*u3[j];
    for (int i = 0; i < 3; i++)
        t[i] = ct[i] - (R[i][0]*cs[0] + R[i][1]*cs[1] + R[i][2]*cs[2]);
}

// ------------------------------- kernels -------------------------------

__global__ void k_init(const float* __restrict__ src, float* __restrict__ temporal,
                       float* __restrict__ Rt_g, float* __restrict__ errlast,
                       int* __restrict__ done_g, unsigned int* __restrict__ ticket) {
    int i = blockIdx.x * blockDim.x + threadIdx.x;   // 0 .. 49151
    temporal[i] = src[i];
    if (blockIdx.x == 0) {
        int tid = threadIdx.x;
        if (tid < BATCH*12) {
            int j = tid % 12;
            Rt_g[tid] = (j < 9 && (j & 3) == 0) ? 1.0f : 0.0f;  // identity | 0
        }
        if (tid < BATCH) errlast[tid] = 0.0f;
        if (tid == 0) { *done_g = 0; *ticket = 0u; }
    }
}

// One dispatch per ICP step. Grid 512 x 256.
// Phase 1 (all blocks): apply prev Rt to own 32 points (write back), 1-NN scan
//   vs LDS-staged targets, wave butterfly argmin, block partial Kabsch sums.
// Phase 2 (last block via atomic ticket + threadfence): global reduce,
//   convergence check, Kabsch -> Rt for NEXT dispatch.
__global__ __launch_bounds__(TPB, 2)
void k_step(const float* __restrict__ tgt, float* __restrict__ temporal,
            double* __restrict__ part_g, float* __restrict__ Rt_g,
            float* __restrict__ errlast, int* __restrict__ done_g,
            unsigned int* __restrict__ ticket) {
    if (*done_g) return;   // converged: state frozen (Rt is identity already)

    __shared__ float4 t4c[CHUNK];        // 32 KB: (x,y,z, 0.5*|t|^2)
    __shared__ double pmem[4][16];       // per-wave partials
    __shared__ double Ssh[4][16];        // last block: per-batch sums
    __shared__ int    islast_sh;
    __shared__ int    convsh;

    const int bid  = blockIdx.x;
    const int b    = bid >> 7;
    const int lb   = bid & (BLK_PER_B - 1);
    const int tid  = threadIdx.x;
    const int w    = tid >> 6;           // wave 0..3 owns 8 points
    const int lane = tid & 63;

    const float* tgb = tgt + (size_t)b * MPTS * 3;
    float* tpb = temporal + ((size_t)b * NPTS + lb * PTS_PER_BLK + w * 8) * 3;

    // apply previous step's transform (identity at s=0)
    const float* rt = Rt_g + b * 12;
    const float r0=rt[0], r1=rt[1], r2=rt[2], r3=rt[3], r4=rt[4], r5=rt[5];
    const float r6=rt[6], r7=rt[7], r8=rt[8], t0=rt[9], t1=rt[10], t2=rt[11];

    float px[8], py[8], pz[8];
    #pragma unroll
    for (int k = 0; k < 8; k++) {
        float x = tpb[3*k+0], y = tpb[3*k+1], z = tpb[3*k+2];
        px[k] = r0*x + r1*y + r2*z + t0;
        py[k] = r3*x + r4*y + r5*z + t1;
        pz[k] = r6*x + r7*y + r8*z + t2;
    }
    if (lane == 0) {
        #pragma unroll
        for (int k = 0; k < 8; k++) {
            tpb[3*k+0] = px[k]; tpb[3*k+1] = py[k]; tpb[3*k+2] = pz[k];
        }
    }

    // ---- 1-NN scan: score = 0.5|t|^2 - p.t  (d2 = |p|^2 + 2*score) ----
    float bs[8]; int bm[8];
    #pragma unroll
    for (int k = 0; k < 8; k++) { bs[k] = 1e30f; bm[k] = 0; }

    for (int h = 0; h < NCHUNK; ++h) {
        __syncthreads();   // WAR vs previous chunk's readers
        for (int i = tid; i < CHUNK; i += TPB) {
            int m = h * CHUNK + i;
            float x = tgb[3*m], y = tgb[3*m+1], z = tgb[3*m+2];
            float hw = 0.5f * (x*x + y*y + z*z);
            t4c[i] = make_float4(x, y, z, hw);
        }
        __syncthreads();
        #pragma unroll 4
        for (int j = 0; j < CHUNK/64; ++j) {      // 32 iters; lane covers m%64==lane
            int ml = (j << 6) | lane;
            float4 T = t4c[ml];
            int m = h * CHUNK + ml;
            #pragma unroll
            for (int k = 0; k < 8; k++) {
                float sc = __fmaf_rn(-px[k], T.x, T.w);
                sc = __fmaf_rn(-py[k], T.y, sc);
                sc = __fmaf_rn(-pz[k], T.z, sc);
                if (sc < bs[k]) { bs[k] = sc; bm[k] = m; }   // first-min per lane
            }
        }
    }

    // full-wave butterfly argmin with exact first-min (smallest m) tie rule
    #pragma unroll
    for (int off = 32; off >= 1; off >>= 1) {
        #pragma unroll
        for (int k = 0; k < 8; k++) {
            float os = __shfl_xor(bs[k], off);
            int   om = __shfl_xor(bm[k], off);
            if (os < bs[k] || (os == bs[k] && om < bm[k])) { bs[k] = os; bm[k] = om; }
        }
    }

    // wave leader: partial Kabsch sums for its 8 points
    if (lane == 0) {
        double acc[16];
        #pragma unroll
        for (int i = 0; i < 16; i++) acc[i] = 0.0;
        #pragma unroll
        for (int k = 0; k < 8; k++) {
            int mm = bm[k];
            float qx = tgb[3*mm], qy = tgb[3*mm+1], qz = tgb[3*mm+2];
            float a2 = px[k]*px[k] + py[k]*py[k] + pz[k]*pz[k];
            float d2 = fmaxf(a2 + 2.0f*bs[k], 0.0f);
            double pxd = px[k], pyd = py[k], pzd = pz[k];
            double qxd = qx,   qyd = qy,   qzd = qz;
            acc[0] += pxd;  acc[1] += pyd;  acc[2] += pzd;
            acc[3] += qxd;  acc[4] += qyd;  acc[5] += qzd;
            acc[6] += pxd*qxd;  acc[7]  += pxd*qyd;  acc[8]  += pxd*qzd;
            acc[9] += pyd*qxd;  acc[10] += pyd*qyd;  acc[11] += pyd*qzd;
            acc[12]+= pzd*qxd;  acc[13] += pzd*qyd;  acc[14] += pzd*qzd;
            acc[15]+= (double)sqrtf(d2);
        }
        #pragma unroll
        for (int i = 0; i < 16; i++) pmem[w][i] = acc[i];
    }
    __syncthreads();
    if (tid < 16)
        part_g[bid * 16 + tid] = pmem[0][tid] + pmem[1][tid] + pmem[2][tid] + pmem[3][tid];
    __syncthreads();

    // ---- last-block retirement ----
    if (tid == 0) {
        __threadfence();                       // release part_g stores (device scope)
        unsigned int t = atomicAdd(ticket, 1u);
        islast_sh = (t == NBLOCKS - 1) ? 1 : 0;
    }
    __syncthreads();
    if (!islast_sh) return;

    __threadfence();                           // acquire other blocks' part_g
    {
        // wave w reduces batch w: lane -> value v=lane&15, quarter c=lane>>4
        int v = lane & 15, c = lane >> 4;
        double ssum = 0.0;
        for (int r = 0; r < 32; r++)
            ssum += part_g[((w << 7) + (c << 5) + r) * 16 + v];
        ssum += __shfl_xor(ssum, 16);
        ssum += __shfl_xor(ssum, 32);
        if (lane < 16) Ssh[w][lane] = ssum;
    }
    __syncthreads();
    if (tid == 0) {
        float e[BATCH];
        bool conv = true;
        for (int bb = 0; bb < BATCH; bb++) {
            e[bb] = (float)(Ssh[bb][15] / (double)NPTS);
            conv = conv && (fabsf(e[bb] - errlast[bb]) < ICP_TOL);
        }
        convsh = conv ? 1 : 0;
        *done_g = conv ? 1 : 0;
        if (!conv)
            for (int bb = 0; bb < BATCH; bb++) errlast[bb] = e[bb];
        *ticket = 0u;                          // reset for next dispatch
    }
    __syncthreads();
    if (tid < BATCH) {
        float* o = Rt_g + tid * 12;
        if (convsh) {
            #pragma unroll
            for (int j = 0; j < 12; j++) o[j] = (j < 9 && (j & 3) == 0) ? 1.0f : 0.0f;
        } else {
            double S[16];
            #pragma unroll
            for (int i = 0; i < 16; i++) S[i] = Ssh[tid][i];
            double R[3][3], t[3];
            kabsch_from_sums(S, R, t);
            o[0] = (float)R[0][0]; o[1]  = (float)R[0][1]; o[2]  = (float)R[0][2];
            o[3] = (float)R[1][0]; o[4]  = (float)R[1][1]; o[5]  = (float)R[1][2];
            o[6] = (float)R[2][0]; o[7]  = (float)R[2][1]; o[8]  = (float)R[2][2];
            o[9] = (float)t[0];    o[10] = (float)t[1];    o[11] = (float)t[2];
        }
    }
}

// final: apply last Rt to temporal, then Kabsch(source -> temporal), out [B,3,4]
__global__ void k_final(const float* __restrict__ source, const float* __restrict__ temporal,
                        const float* __restrict__ Rt_g, float* __restrict__ out) {
    const int tid = threadIdx.x;
    const int b = tid >> 8;
    const int lb = tid & 255;

    const float* rt = Rt_g + b * 12;
    const float r0=rt[0], r1=rt[1], r2=rt[2], r3=rt[3], r4=rt[4], r5=rt[5];
    const float r6=rt[6], r7=rt[7], r8=rt[8], t0=rt[9], t1=rt[10], t2=rt[11];

    double acc[16];
    #pragma unroll
    for (int i = 0; i < 16; i++) acc[i] = 0.0;

    for (int k = 0; k < NPTS/256; ++k) {
        int n = lb + k*256;
        const float* tp = source   + ((size_t)b*NPTS + n)*3;
        const float* tq = temporal + ((size_t)b*NPTS + n)*3;
        float qx0 = tq[0], qy0 = tq[1], qz0 = tq[2];
        float qxf = r0*qx0 + r1*qy0 + r2*qz0 + t0;
        float qyf = r3*qx0 + r4*qy0 + r5*qz0 + t1;
        float qzf = r6*qx0 + r7*qy0 + r8*qz0 + t2;
        double px = tp[0], py = tp[1], pz = tp[2];
        double qx = qxf, qy = qyf, qz = qzf;
        acc[0] += px;  acc[1] += py;  acc[2] += pz;
        acc[3] += qx;  acc[4] += qy;  acc[5] += qz;
        acc[6] += px*qx;  acc[7]  += px*qy;  acc[8]  += px*qz;
        acc[9] += py*qx;  acc[10] += py*qy;  acc[11] += py*qz;
        acc[12]+= pz*qx;  acc[13] += pz*qy;  acc[14] += pz*qz;
    }

    #pragma unroll
    for (int off = 32; off > 0; off >>= 1)
        #pragma unroll
        for (int i = 0; i < 15; i++) acc[i] += __shfl_down(acc[i], off);

    __shared__ double part[16][16];
    const int wave = tid >> 6;
    if ((tid & 63) == 0) {
        #pragma unroll
        for (int i = 0; i < 15; i++) part[wave][i] = acc[i];
    }
    __syncthreads();

    if (tid < BATCH) {
        double S[16];
        #pragma unroll
        for (int i = 0; i < 15; i++)
            S[i] = part[tid*4][i] + part[tid*4+1][i] + part[tid*4+2][i] + part[tid*4+3][i];
        S[15] = 0.0;
        double R[3][3], t[3];
        kabsch_from_sums(S, R, t);
        float* o = out + tid*12;
        #pragma unroll
        for (int i = 0; i < 3; i++) {
            o[i*4+0] = (float)R[i][0];
            o[i*4+1] = (float)R[i][1];
            o[i*4+2] = (float)R[i][2];
            o[i*4+3] = (float)t[i];
        }
    }
}

// ----------------------------- launcher -----------------------------

extern "C" void kernel_launch(void* const* d_in, const int* in_sizes, int n_in,
                              void* d_out, int out_size, void* d_ws, size_t ws_size,
                              hipStream_t stream) {
    const float* src = (const float*)d_in[0];
    const float* tgt = (const float*)d_in[1];
    float* out = (float*)d_out;

    char* ws = (char*)d_ws;
    float*  temporal = (float*)ws;                         // 4*4096*3*4   = 196608 B
    double* part_g   = (double*)(ws + 196608);             // 512*16*8     =  65536 B
    float*  Rt_g     = (float*)(ws + 262144);              // 4*12*4       =    192 B
    float*  errlast  = (float*)(ws + 262336);              // 16 B
    int*    done_g   = (int*)(ws + 262352);                // 4 B
    unsigned int* ticket = (unsigned int*)(ws + 262356);   // 4 B

    k_init<<<dim3(192), dim3(256), 0, stream>>>(src, temporal, Rt_g, errlast, done_g, ticket);

    for (int s = 0; s < NSTEPS; ++s)
        k_step<<<dim3(NBLOCKS), dim3(TPB), 0, stream>>>(tgt, temporal, part_g, Rt_g,
                                                        errlast, done_g, ticket);

    k_final<<<dim3(1), dim3(1024), 0, stream>>>(src, temporal, Rt_g, out);
}